// Round 2
// baseline (1780.720 us; speedup 1.0000x reference)
//
#include <hip/hip_runtime.h>

#define E_EDGES 3200000
#define N_NODES_K 100000
#define NEG_INF_F (-10000000000.0f)

// monotonic float->uint key for atomicMax on floats (handles negatives)
__device__ __forceinline__ unsigned fkey(float x) {
    unsigned u = __float_as_uint(x);
    return (u & 0x80000000u) ? ~u : (u | 0x80000000u);
}
__device__ __forceinline__ float fkey_inv(unsigned k) {
    return (k & 0x80000000u) ? __uint_as_float(k ^ 0x80000000u) : __uint_as_float(~k);
}

// ---------------------------------------------------------------------------
// K0: one wave — dtype detection + scalar init
//   flags[0]: edge_index int64 (1) / int32 (0)
//   flags[1]: selection int32 words (0), bytes (1), float32 (2)
// ---------------------------------------------------------------------------
__global__ __launch_bounds__(64) void k_init(const unsigned* ei_w, const unsigned* sel_w,
                                             unsigned* maxkey, float* sum, int* flags,
                                             int* count) {
    const int lane = threadIdx.x;
    unsigned hw = ei_w[2 * (lane + 1) + 1];  // hi-word if int64 (values < 2^17)
    unsigned long long anyhi = __ballot(hw != 0u);
    unsigned sv = sel_w[lane];
    unsigned long long not01 = __ballot(sv != 0u && sv != 1u);
    unsigned long long notf  = __ballot(sv != 0u && sv != 0x3F800000u);
    if (lane == 0) {
        flags[0] = (anyhi == 0ull) ? 1 : 0;
        flags[1] = (not01 == 0ull) ? 0 : ((notf == 0ull) ? 2 : 1);
        *maxkey = fkey(-3.0e38f);
        *sum = 0.0f;
        *count = 0;
    }
}

// ---------------------------------------------------------------------------
// KP: P1[n] = node_reps[n] @ W1[0:32,:] + b1,  P2[n] = node_reps[n] @ W1[32:64,:]
// ---------------------------------------------------------------------------
__global__ __launch_bounds__(256) void k_nodeproj(
    const float* __restrict__ nr, const float* __restrict__ W1,
    const float* __restrict__ b1, float* __restrict__ P1, float* __restrict__ P2) {
    int n = blockIdx.x * 256 + threadIdx.x;
    if (n >= N_NODES_K) return;
    const float4* x4 = (const float4*)(nr + (size_t)n * 32);
    float xr[32];
#pragma unroll
    for (int i = 0; i < 8; ++i) {
        float4 t = x4[i];
        xr[4 * i + 0] = t.x; xr[4 * i + 1] = t.y; xr[4 * i + 2] = t.z; xr[4 * i + 3] = t.w;
    }
    float4* o1 = (float4*)(P1 + (size_t)n * 32);
    float4* o2 = (float4*)(P2 + (size_t)n * 32);
#pragma unroll
    for (int jb = 0; jb < 8; ++jb) {
        const float4 bb = *(const float4*)(b1 + jb * 4);
        float4 a1 = make_float4(bb.x, bb.y, bb.z, bb.w);
        float4 a2 = make_float4(0.f, 0.f, 0.f, 0.f);
#pragma unroll
        for (int k = 0; k < 32; ++k) {
            float xv = xr[k];
            const float4 w1 = *(const float4*)(W1 + (size_t)k * 32 + jb * 4);
            const float4 w2 = *(const float4*)(W1 + (size_t)(32 + k) * 32 + jb * 4);
            a1.x = fmaf(xv, w1.x, a1.x); a1.y = fmaf(xv, w1.y, a1.y);
            a1.z = fmaf(xv, w1.z, a1.z); a1.w = fmaf(xv, w1.w, a1.w);
            a2.x = fmaf(xv, w2.x, a2.x); a2.y = fmaf(xv, w2.y, a2.y);
            a2.z = fmaf(xv, w2.z, a2.z); a2.w = fmaf(xv, w2.w, a2.w);
        }
        o1[jb] = a1; o2[jb] = a2;
    }
}

// ---------------------------------------------------------------------------
// KC: stream-compact active edges -> list[pos] = {e, s, d, 0};
//     masked edges get scores[e] = NEG_INF (so exp -> 0 downstream).
// ---------------------------------------------------------------------------
__global__ __launch_bounds__(256) void k_compact(
    const void* __restrict__ ei_raw, const void* __restrict__ sel_raw,
    const int* __restrict__ flags, int4* __restrict__ list,
    int* __restrict__ count, float* __restrict__ scores) {
    const int e = blockIdx.x * 256 + threadIdx.x;
    const int fei = flags[0], fsel = flags[1];

    bool act;
    if (fsel == 0)      act = ((const int*)sel_raw)[e] == 0;
    else if (fsel == 1) act = ((const unsigned char*)sel_raw)[e] == 0;
    else                act = ((const float*)sel_raw)[e] == 0.0f;

    int s = 0, d = 0;
    if (act) {
        const int* ei = (const int*)ei_raw;
        if (fei) { s = ei[2 * (size_t)e]; d = ei[2 * ((size_t)E_EDGES + e)]; }
        else     { s = ei[e];             d = ei[E_EDGES + e]; }
    }

    unsigned long long m = __ballot(act);
    const int lane = threadIdx.x & 63, wid = threadIdx.x >> 6;
    int lpos = __popcll(m & ((1ull << lane) - 1ull));
    __shared__ int wbase[4];
    __shared__ int bbase;
    if (lane == 0) wbase[wid] = __popcll(m);
    __syncthreads();
    if (threadIdx.x == 0) {
        int t0 = wbase[0], t1 = wbase[1], t2 = wbase[2], t3 = wbase[3];
        wbase[0] = 0; wbase[1] = t0; wbase[2] = t0 + t1; wbase[3] = t0 + t1 + t2;
        bbase = atomicAdd(count, t0 + t1 + t2 + t3);
    }
    __syncthreads();
    if (act) list[(size_t)bbase + wbase[wid] + lpos] = make_int4(e, s, d, 0);
    else     scores[e] = NEG_INF_F;
}

// ---------------------------------------------------------------------------
// KE: compacted edge scores. 2 edges/thread, W1[64:96] + gdiff staged in LDS.
//     score = elu(P1[s] + P2[d] + er[e] @ W3) . gdiff ; block max -> atomicMax.
// ---------------------------------------------------------------------------
#define KE_BLOCKS 2048
__global__ __launch_bounds__(256) void k_edge(
    const float* __restrict__ er_, const float* __restrict__ W1,
    const float* __restrict__ gr, const float* __restrict__ sgr,
    const int4* __restrict__ list, const int* __restrict__ count,
    const float* __restrict__ P1, const float* __restrict__ P2,
    float* __restrict__ scores, unsigned* __restrict__ maxkey) {
    __shared__ float sW[1024];   // W1[64:96][:] row-major [k][j]
    __shared__ float sGd[32];    // graph_rep - subgraph_rep
    __shared__ float smax[4];
    const int tid = threadIdx.x;
    ((float4*)sW)[tid] = ((const float4*)(W1 + 64 * 32))[tid];
    if (tid < 32) sGd[tid] = gr[tid] - sgr[tid];
    __syncthreads();

    const int cnt = *count;
    float lmax = -3.0e38f;

    for (int base = blockIdx.x * 512; base < cnt; base += KE_BLOCKS * 512) {
        const int i0 = base + tid, i1 = i0 + 256;
        const bool a0 = i0 < cnt, a1 = i1 < cnt;
        int4 r0 = a0 ? list[i0] : make_int4(0, 0, 0, 0);
        int4 r1 = a1 ? list[i1] : make_int4(0, 0, 0, 0);

        // edge-rep rows
        float4 x0[8], x1[8];
        const float4* e0p = (const float4*)(er_ + (size_t)r0.x * 32);
        const float4* e1p = (const float4*)(er_ + (size_t)r1.x * 32);
#pragma unroll
        for (int i = 0; i < 8; ++i) { x0[i] = e0p[i]; x1[i] = e1p[i]; }

        // acc init = P1[s] + P2[d]   (b1 folded into P1)
        float acc0[32], acc1[32];
        const float4* p10 = (const float4*)(P1 + (size_t)r0.y * 32);
        const float4* p20 = (const float4*)(P2 + (size_t)r0.z * 32);
        const float4* p11 = (const float4*)(P1 + (size_t)r1.y * 32);
        const float4* p21 = (const float4*)(P2 + (size_t)r1.z * 32);
#pragma unroll
        for (int jb = 0; jb < 8; ++jb) {
            float4 a = p10[jb], b = p20[jb];
            acc0[4 * jb + 0] = a.x + b.x; acc0[4 * jb + 1] = a.y + b.y;
            acc0[4 * jb + 2] = a.z + b.z; acc0[4 * jb + 3] = a.w + b.w;
            float4 c = p11[jb], dd = p21[jb];
            acc1[4 * jb + 0] = c.x + dd.x; acc1[4 * jb + 1] = c.y + dd.y;
            acc1[4 * jb + 2] = c.z + dd.z; acc1[4 * jb + 3] = c.w + dd.w;
        }

        // z += x @ W3   (W3 uniform from LDS, shared across the 2 edges)
#pragma unroll
        for (int kb = 0; kb < 8; ++kb) {
            const float* xv0 = (const float*)&x0[kb];
            const float* xv1 = (const float*)&x1[kb];
#pragma unroll
            for (int kc = 0; kc < 4; ++kc) {
                const float e0 = xv0[kc], e1 = xv1[kc];
                const int k = kb * 4 + kc;
#pragma unroll
                for (int jb = 0; jb < 8; ++jb) {
                    const float4 w = *(const float4*)&sW[k * 32 + jb * 4];
                    acc0[4 * jb + 0] = fmaf(e0, w.x, acc0[4 * jb + 0]);
                    acc0[4 * jb + 1] = fmaf(e0, w.y, acc0[4 * jb + 1]);
                    acc0[4 * jb + 2] = fmaf(e0, w.z, acc0[4 * jb + 2]);
                    acc0[4 * jb + 3] = fmaf(e0, w.w, acc0[4 * jb + 3]);
                    acc1[4 * jb + 0] = fmaf(e1, w.x, acc1[4 * jb + 0]);
                    acc1[4 * jb + 1] = fmaf(e1, w.y, acc1[4 * jb + 1]);
                    acc1[4 * jb + 2] = fmaf(e1, w.z, acc1[4 * jb + 2]);
                    acc1[4 * jb + 3] = fmaf(e1, w.w, acc1[4 * jb + 3]);
                }
            }
        }

        // elu + dot(gdiff)
        float sc0 = 0.0f, sc1 = 0.0f;
#pragma unroll
        for (int jb = 0; jb < 8; ++jb) {
            const float4 g = *(const float4*)&sGd[jb * 4];
            const float* gp = (const float*)&g;
#pragma unroll
            for (int c = 0; c < 4; ++c) {
                float z0 = acc0[4 * jb + c];
                float h0 = z0 > 0.0f ? z0 : (__expf(z0) - 1.0f);
                sc0 = fmaf(h0, gp[c], sc0);
                float z1 = acc1[4 * jb + c];
                float h1 = z1 > 0.0f ? z1 : (__expf(z1) - 1.0f);
                sc1 = fmaf(h1, gp[c], sc1);
            }
        }

        if (a0) { scores[r0.x] = sc0; lmax = fmaxf(lmax, sc0); }
        if (a1) { scores[r1.x] = sc1; lmax = fmaxf(lmax, sc1); }
    }

    // block max -> one atomic
#pragma unroll
    for (int off = 32; off > 0; off >>= 1) lmax = fmaxf(lmax, __shfl_down(lmax, off));
    const int lane = tid & 63, wid = tid >> 6;
    if (lane == 0) smax[wid] = lmax;
    __syncthreads();
    if (tid == 0) {
        float m = fmaxf(fmaxf(smax[0], smax[1]), fmaxf(smax[2], smax[3]));
        atomicMax(maxkey, fkey(m));
    }
}

// ---------------------------------------------------------------------------
// KS: sum += exp((score-max)*2)   (read-only over scores)
// ---------------------------------------------------------------------------
__global__ __launch_bounds__(256) void k_sum(
    const float* __restrict__ scores, const unsigned* __restrict__ maxkey,
    float* __restrict__ sum) {
    const int i = blockIdx.x * 256 + threadIdx.x;
    const float mx = fkey_inv(*maxkey);
    float4 s = ((const float4*)scores)[i];
    float v = __expf((s.x - mx) * 2.0f) + __expf((s.y - mx) * 2.0f) +
              __expf((s.z - mx) * 2.0f) + __expf((s.w - mx) * 2.0f);
#pragma unroll
    for (int off = 32; off > 0; off >>= 1) v += __shfl_down(v, off);
    __shared__ float ssum[4];
    const int lane = threadIdx.x & 63, wid = threadIdx.x >> 6;
    if (lane == 0) ssum[wid] = v;
    __syncthreads();
    if (threadIdx.x == 0) atomicAdd(sum, ssum[0] + ssum[1] + ssum[2] + ssum[3]);
}

// ---------------------------------------------------------------------------
// KF: out = exp((score-max)*2) / sum
// ---------------------------------------------------------------------------
__global__ __launch_bounds__(256) void k_fin(
    const float* __restrict__ scores, const unsigned* __restrict__ maxkey,
    const float* __restrict__ sum, float* __restrict__ out) {
    const int i = blockIdx.x * 256 + threadIdx.x;
    const float mx = fkey_inv(*maxkey);
    const float r = 1.0f / *sum;
    float4 s = ((const float4*)scores)[i];
    float4 o;
    o.x = __expf((s.x - mx) * 2.0f) * r;
    o.y = __expf((s.y - mx) * 2.0f) * r;
    o.z = __expf((s.z - mx) * 2.0f) * r;
    o.w = __expf((s.w - mx) * 2.0f) * r;
    ((float4*)out)[i] = o;
}

extern "C" void kernel_launch(void* const* d_in, const int* in_sizes, int n_in,
                              void* d_out, int out_size, void* d_ws, size_t ws_size,
                              hipStream_t stream) {
    const float* node_reps    = (const float*)d_in[0];
    const float* edge_reps    = (const float*)d_in[1];
    const float* graph_rep    = (const float*)d_in[2];
    const float* subgraph_rep = (const float*)d_in[3];
    const float* W1           = (const float*)d_in[4];
    const float* b1           = (const float*)d_in[5];
    const void*  ei           = d_in[6];
    const void*  selp         = d_in[7];
    float* out = (float*)d_out;

    char* ws = (char*)d_ws;
    float* P1     = (float*)ws;                                        // 12.8 MB
    float* P2     = (float*)(ws + (size_t)N_NODES_K * 32 * 4);         // 12.8 MB
    float* scores = (float*)(ws + (size_t)2 * N_NODES_K * 32 * 4);     // 12.8 MB
    int4*  list   = (int4*)(ws + (size_t)2 * N_NODES_K * 32 * 4 + (size_t)E_EDGES * 4); // 51.2 MB
    char* scal = ws + (size_t)2 * N_NODES_K * 32 * 4 + (size_t)E_EDGES * 4 +
                 (size_t)E_EDGES * 16;
    unsigned* maxkey = (unsigned*)scal;
    float*    sum    = (float*)(scal + 4);
    int*      flags  = (int*)(scal + 8);
    int*      count  = (int*)(scal + 16);

    k_init<<<1, 64, 0, stream>>>((const unsigned*)ei, (const unsigned*)selp,
                                 maxkey, sum, flags, count);
    k_nodeproj<<<(N_NODES_K + 255) / 256, 256, 0, stream>>>(node_reps, W1, b1, P1, P2);
    k_compact<<<E_EDGES / 256, 256, 0, stream>>>(ei, selp, flags, list, count, scores);
    k_edge<<<KE_BLOCKS, 256, 0, stream>>>(edge_reps, W1, graph_rep, subgraph_rep,
                                          list, count, P1, P2, scores, maxkey);
    k_sum<<<E_EDGES / 4 / 256, 256, 0, stream>>>(scores, maxkey, sum);
    k_fin<<<E_EDGES / 4 / 256, 256, 0, stream>>>(scores, maxkey, sum, out);
}

// Round 3
// 208.597 us; speedup vs baseline: 8.5367x; 8.5367x over previous
//
#include <hip/hip_runtime.h>

#define E_EDGES 3200000
#define N_NODES_K 100000
#define NEG_INF_F (-10000000000.0f)
#define KE_NB (E_EDGES / 256)   // 12500 blocks

// ---------------------------------------------------------------------------
// K0: one wave — dtype detection + scalar init
//   flags[0]: edge_index int64 (1) / int32 (0)
//   flags[1]: selection int32 words (0), bytes (1), float32 (2)
// ---------------------------------------------------------------------------
__global__ __launch_bounds__(64) void k_init(const unsigned* ei_w, const unsigned* sel_w,
                                             int* flags) {
    const int lane = threadIdx.x;
    unsigned hw = ei_w[2 * (lane + 1) + 1];  // hi-word if int64 (values < 2^17)
    unsigned long long anyhi = __ballot(hw != 0u);
    unsigned sv = sel_w[lane];
    unsigned long long not01 = __ballot(sv != 0u && sv != 1u);
    unsigned long long notf  = __ballot(sv != 0u && sv != 0x3F800000u);
    if (lane == 0) {
        flags[0] = (anyhi == 0ull) ? 1 : 0;
        flags[1] = (not01 == 0ull) ? 0 : ((notf == 0ull) ? 2 : 1);
    }
}

// ---------------------------------------------------------------------------
// KP: P1[n] = node_reps[n] @ W1[0:32,:] + b1,  P2[n] = node_reps[n] @ W1[32:64,:]
// ---------------------------------------------------------------------------
__global__ __launch_bounds__(256) void k_nodeproj(
    const float* __restrict__ nr, const float* __restrict__ W1,
    const float* __restrict__ b1, float* __restrict__ P1, float* __restrict__ P2) {
    int n = blockIdx.x * 256 + threadIdx.x;
    if (n >= N_NODES_K) return;
    const float4* x4 = (const float4*)(nr + (size_t)n * 32);
    float xr[32];
#pragma unroll
    for (int i = 0; i < 8; ++i) {
        float4 t = x4[i];
        xr[4 * i + 0] = t.x; xr[4 * i + 1] = t.y; xr[4 * i + 2] = t.z; xr[4 * i + 3] = t.w;
    }
    float4* o1 = (float4*)(P1 + (size_t)n * 32);
    float4* o2 = (float4*)(P2 + (size_t)n * 32);
#pragma unroll
    for (int jb = 0; jb < 8; ++jb) {
        const float4 bb = *(const float4*)(b1 + jb * 4);
        float4 a1 = make_float4(bb.x, bb.y, bb.z, bb.w);
        float4 a2 = make_float4(0.f, 0.f, 0.f, 0.f);
#pragma unroll
        for (int k = 0; k < 32; ++k) {
            float xv = xr[k];
            const float4 w1 = *(const float4*)(W1 + (size_t)k * 32 + jb * 4);
            const float4 w2 = *(const float4*)(W1 + (size_t)(32 + k) * 32 + jb * 4);
            a1.x = fmaf(xv, w1.x, a1.x); a1.y = fmaf(xv, w1.y, a1.y);
            a1.z = fmaf(xv, w1.z, a1.z); a1.w = fmaf(xv, w1.w, a1.w);
            a2.x = fmaf(xv, w2.x, a2.x); a2.y = fmaf(xv, w2.y, a2.y);
            a2.z = fmaf(xv, w2.z, a2.z); a2.w = fmaf(xv, w2.w, a2.w);
        }
        o1[jb] = a1; o2[jb] = a2;
    }
}

// ---------------------------------------------------------------------------
// KE: direct per-edge. score = elu(P1[s]+P2[d]+er[e]@W3) . gdiff  (b1 in P1)
//     masked -> NEG_INF. Per-block (max, sum_exp_local) written out.
// ---------------------------------------------------------------------------
__global__ __launch_bounds__(256) void k_edge(
    const float* __restrict__ er_, const float* __restrict__ W1,
    const float* __restrict__ gr, const float* __restrict__ sgr,
    const void* __restrict__ ei_raw, const void* __restrict__ sel_raw,
    const int* __restrict__ flags,
    const float* __restrict__ P1, const float* __restrict__ P2,
    float* __restrict__ scores, float* __restrict__ bmax,
    float* __restrict__ bsum) {
    __shared__ float sW[1024];   // W1[64:96][:] row-major [k][j]
    __shared__ float sGd[32];
    __shared__ float sred[8];
    const int tid = threadIdx.x;
    ((float4*)sW)[tid] = ((const float4*)(W1 + 64 * 32))[tid];
    if (tid < 32) sGd[tid] = gr[tid] - sgr[tid];

    const int e = blockIdx.x * 256 + tid;
    const int fei = flags[0], fsel = flags[1];
    bool act;
    if (fsel == 0)      act = ((const int*)sel_raw)[e] == 0;
    else if (fsel == 1) act = ((const unsigned char*)sel_raw)[e] == 0;
    else                act = ((const float*)sel_raw)[e] == 0.0f;

    int s = 0, d = 0;
    if (act) {
        if (fei) {
            int2 vs = ((const int2*)ei_raw)[e];
            int2 vd = ((const int2*)ei_raw)[E_EDGES + e];
            s = vs.x; d = vd.x;
        } else {
            const int* ei = (const int*)ei_raw;
            s = ei[e]; d = ei[E_EDGES + e];
        }
    }
    __syncthreads();   // sW / sGd ready

    float score = NEG_INF_F;
    if (act) {
        float acc[32];
        const float4* p1 = (const float4*)(P1 + (size_t)s * 32);
        const float4* p2 = (const float4*)(P2 + (size_t)d * 32);
#pragma unroll
        for (int jb = 0; jb < 8; ++jb) {
            float4 a = p1[jb], b = p2[jb];
            acc[4 * jb + 0] = a.x + b.x; acc[4 * jb + 1] = a.y + b.y;
            acc[4 * jb + 2] = a.z + b.z; acc[4 * jb + 3] = a.w + b.w;
        }
        const float4* e4 = (const float4*)(er_ + (size_t)e * 32);
#pragma unroll
        for (int kb = 0; kb < 8; ++kb) {
            float4 x = e4[kb];
            const float* xp = (const float*)&x;
#pragma unroll
            for (int kc = 0; kc < 4; ++kc) {
                const float ek = xp[kc];
                const int k = kb * 4 + kc;
#pragma unroll
                for (int jb = 0; jb < 8; ++jb) {
                    const float4 w = *(const float4*)&sW[k * 32 + jb * 4];
                    acc[4 * jb + 0] = fmaf(ek, w.x, acc[4 * jb + 0]);
                    acc[4 * jb + 1] = fmaf(ek, w.y, acc[4 * jb + 1]);
                    acc[4 * jb + 2] = fmaf(ek, w.z, acc[4 * jb + 2]);
                    acc[4 * jb + 3] = fmaf(ek, w.w, acc[4 * jb + 3]);
                }
            }
        }
        float sc = 0.0f;
#pragma unroll
        for (int j = 0; j < 32; ++j) {
            float z = acc[j];
            float h = z > 0.0f ? z : (__expf(z) - 1.0f);
            sc = fmaf(h, sGd[j], sc);
        }
        score = sc;
    }
    scores[e] = score;

    // block max
    float m = score;
#pragma unroll
    for (int off = 32; off > 0; off >>= 1) m = fmaxf(m, __shfl_down(m, off));
    const int lane = tid & 63, wid = tid >> 6;
    if (lane == 0) sred[wid] = m;
    __syncthreads();
    const float mb = fmaxf(fmaxf(sred[0], sred[1]), fmaxf(sred[2], sred[3]));
    // block sum of exp((score - mb)/T); all-masked block -> mb=NEG_INF -> handled
    float v = __expf((score - mb) * 2.0f);
#pragma unroll
    for (int off = 32; off > 0; off >>= 1) v += __shfl_down(v, off);
    __syncthreads();
    if (lane == 0) sred[4 + wid] = v;
    __syncthreads();
    if (tid == 0) {
        bmax[blockIdx.x] = mb;
        bsum[blockIdx.x] = sred[4] + sred[5] + sred[6] + sred[7];
    }
}

// ---------------------------------------------------------------------------
// KR: one block — global max + rescaled sum over 12500 block partials
// ---------------------------------------------------------------------------
__global__ __launch_bounds__(256) void k_reduce(
    const float* __restrict__ bmax, const float* __restrict__ bsum,
    float* __restrict__ mx_out, float* __restrict__ rsum_out) {
    const int tid = threadIdx.x;
    __shared__ float sm[4];
    float m = -3.0e38f;
    for (int i = tid; i < KE_NB; i += 256) m = fmaxf(m, bmax[i]);
#pragma unroll
    for (int off = 32; off > 0; off >>= 1) m = fmaxf(m, __shfl_down(m, off));
    const int lane = tid & 63, wid = tid >> 6;
    if (lane == 0) sm[wid] = m;
    __syncthreads();
    const float M = fmaxf(fmaxf(sm[0], sm[1]), fmaxf(sm[2], sm[3]));
    float s = 0.0f;
    for (int i = tid; i < KE_NB; i += 256)
        s += bsum[i] * __expf((bmax[i] - M) * 2.0f);
#pragma unroll
    for (int off = 32; off > 0; off >>= 1) s += __shfl_down(s, off);
    __syncthreads();
    __shared__ float ss[4];
    if (lane == 0) ss[wid] = s;
    __syncthreads();
    if (tid == 0) {
        *mx_out = M;
        *rsum_out = 1.0f / (ss[0] + ss[1] + ss[2] + ss[3]);
    }
}

// ---------------------------------------------------------------------------
// KF: out = exp((score - M)/T) * rsum
// ---------------------------------------------------------------------------
__global__ __launch_bounds__(256) void k_fin(
    const float* __restrict__ scores, const float* __restrict__ mx,
    const float* __restrict__ rsum, float* __restrict__ out) {
    const int i = blockIdx.x * 256 + threadIdx.x;
    const float M = *mx;
    const float r = *rsum;
    float4 s = ((const float4*)scores)[i];
    float4 o;
    o.x = __expf((s.x - M) * 2.0f) * r;
    o.y = __expf((s.y - M) * 2.0f) * r;
    o.z = __expf((s.z - M) * 2.0f) * r;
    o.w = __expf((s.w - M) * 2.0f) * r;
    ((float4*)out)[i] = o;
}

extern "C" void kernel_launch(void* const* d_in, const int* in_sizes, int n_in,
                              void* d_out, int out_size, void* d_ws, size_t ws_size,
                              hipStream_t stream) {
    const float* node_reps    = (const float*)d_in[0];
    const float* edge_reps    = (const float*)d_in[1];
    const float* graph_rep    = (const float*)d_in[2];
    const float* subgraph_rep = (const float*)d_in[3];
    const float* W1           = (const float*)d_in[4];
    const float* b1           = (const float*)d_in[5];
    const void*  ei           = d_in[6];
    const void*  selp         = d_in[7];
    float* out = (float*)d_out;

    char* ws = (char*)d_ws;
    size_t off = 0;
    float* P1     = (float*)(ws + off); off += (size_t)N_NODES_K * 32 * 4;  // 12.8 MB
    float* P2     = (float*)(ws + off); off += (size_t)N_NODES_K * 32 * 4;  // 12.8 MB
    float* scores = (float*)(ws + off); off += (size_t)E_EDGES * 4;         // 12.8 MB
    float* bmax   = (float*)(ws + off); off += (size_t)KE_NB * 4;           // 50 KB
    float* bsum   = (float*)(ws + off); off += (size_t)KE_NB * 4;           // 50 KB
    int*   flags  = (int*)(ws + off);   off += 64;
    float* mx     = (float*)(ws + off); off += 4;
    float* rsum   = (float*)(ws + off); off += 4;

    k_init<<<1, 64, 0, stream>>>((const unsigned*)ei, (const unsigned*)selp, flags);
    k_nodeproj<<<(N_NODES_K + 255) / 256, 256, 0, stream>>>(node_reps, W1, b1, P1, P2);
    k_edge<<<KE_NB, 256, 0, stream>>>(edge_reps, W1, graph_rep, subgraph_rep,
                                      ei, selp, flags, P1, P2, scores, bmax, bsum);
    k_reduce<<<1, 256, 0, stream>>>(bmax, bsum, mx, rsum);
    k_fin<<<E_EDGES / 4 / 256, 256, 0, stream>>>(scores, mx, rsum, out);
}